// Round 11
// baseline (329.521 us; speedup 1.0000x reference)
//
#include <hip/hip_runtime.h>
#include <stdint.h>

// Problem constants (from reference)
#define TT 8192          // time length
#define CC 72            // channels
#define PP 7             // patch size
#define NN (TT - PP + 1) // 8186 patches
#define DD (CC * PP)     // 504 patch dim

// ---- pass1 tile geometry (narrow-J, small-LDS engine) ----
#define SGI 128          // S grid rows (X-time)
#define TII 122          // output rows per tile
#define NTI 68           // i-tiles
#define SGJ 64           // S grid cols (Y-time)
#define TIJ 58           // output cols per tile
#define NTJ 142          // j-tiles (142*58 = 8236 >= 8186)
#define NT2 (NTI * NTJ)  // 9656
#define SPADJ 68         // padded S row stride (floats)
#define CH 36            // channels per K-split half

// LDS: Sl[<=134][68] floats = 36608 B (incl. stray-read slack), cmin at +36608
#define SL_BYTES 36608
#define SMEM_TOT (SL_BYTES + 384)
// stage buffers alias Sl: Xs[36][128] @0 (18432 B), Ys[36][64] @18432 (9216 B)

// ---- legacy square engine (hybrid fallback pass2 only) ----
#define TI 122
#define SG 128
#define SPAD 132
#define NTILE 68
#define STAGE_BYTES (CC * SG * 4)
#define SMEM_UNION  (2 * STAGE_BYTES)

#define TAIL_BYTES 196608
#define SROWS 4          // dist rows per stream block

constexpr float INV_D = 1.0f / (float)DD;
constexpr float ALPHA_C = 0.01f;
constexpr float QSCALE = 67108864.0f;        // 2^26 fixed-point for deterministic mean

// ------------------------------------------------------------------
// prep: patch norms sx/sy; init colmin, packed, qsum. (validated)
// ------------------------------------------------------------------
__global__ void prep_kernel(const float* __restrict__ X, const float* __restrict__ Y,
                            float* __restrict__ sx, float* __restrict__ sy,
                            unsigned* __restrict__ colmin,
                            unsigned long long* __restrict__ packed,
                            unsigned long long* __restrict__ qsum) {
    int i = blockIdx.x * 256 + threadIdx.x;
    if (blockIdx.y == 0) {
        if (i == 0) *qsum = 0ULL;
        if (i < TT) { colmin[i] = 0x7f800000u; packed[i] = ~0ULL; }
        if (i < NN) {
            float ax = 0.0f;
            for (int c = 0; c < CC; ++c) {
                const float* xr = X + c * TT + i;
#pragma unroll
                for (int k = 0; k < PP; ++k) { float v = xr[k]; ax += v * v; }
            }
            sx[i] = ax;
        }
    } else {
        if (i < NN) {
            float ay = 0.0f;
            for (int c = 0; c < CC; ++c) {
                const float* yr = Y + c * TT + i;
#pragma unroll
                for (int k = 0; k < PP; ++k) { float w = yr[k]; ay += w * w; }
            }
            sy[i] = ay;
        }
    }
}

// ------------------------------------------------------------------
// pass1: narrow-J small-LDS engine. Numerics BIT-IDENTICAL to the
// validated square engine: each s[a][b] accumulates c = 0..71 ascending
// (K-split 36+36 preserves order), diag k ascending, same dist formula,
// same order-independent min/store semantics. LDS ~37 KB -> 3-4 blocks/CU
// (the 74.7 KB square engine pins at 2; r7 showed the allocator won't
// pair 74.7 KB x2 reliably).
// ------------------------------------------------------------------
__global__ __launch_bounds__(256, 4) void pass1_k(
        const float* __restrict__ X, const float* __restrict__ Y,
        const float* __restrict__ sx, const float* __restrict__ sy,
        unsigned* __restrict__ colmin,
        float* __restrict__ distbuf, int storeTiles) {
    __shared__ __align__(16) char smem[SMEM_TOT];
    float (*Xs)[SGI]   = (float (*)[SGI])smem;             // [36][128], aliases Sl
    float (*Ys)[SGJ]   = (float (*)[SGJ])(smem + 18432);   // [36][64],  aliases Sl
    float (*Sl)[SPADJ] = (float (*)[SPADJ])smem;
    unsigned* cmin_s   = (unsigned*)(smem + SL_BYTES);

    const int tid = threadIdx.x;
    const int su = tid >> 4, sv = tid & 15;
    const int ri = su * 8, rj = sv * 4;

    const int tile = blockIdx.x;
    const int by = tile / NTJ, bx = tile - by * NTJ;
    const int i0 = by * TII, j0 = bx * TIJ;
    const bool store = (by < storeTiles);   // block-uniform

    if (tid < SGJ) cmin_s[tid] = 0x7f800000u;

    // ---- S accumulate with K-split staging (c ascending overall) ----
    float s[8][4];
#pragma unroll
    for (int a = 0; a < 8; ++a)
#pragma unroll
        for (int b = 0; b < 4; ++b) s[a][b] = 0.0f;

    for (int h = 0; h < 2; ++h) {
        // stage half h: X rows 36x128, Y rows 36x64 (same addr/clamp scheme
        // as validated; i0/j0 even -> aligned float2)
        for (int idx = tid; idx < 3456; idx += 256) {
            if (idx < 2304) {
                int cc = idx >> 6;
                int t2 = (idx & 63) * 2;
                int gx = i0 + t2;
                const float* xp = X + (size_t)(CH * h + cc) * TT;
                float2 xv;
                if (gx + 1 < TT) xv = *(const float2*)(xp + gx);
                else { xv.x = xp[min(gx, TT - 1)]; xv.y = xp[min(gx + 1, TT - 1)]; }
                *(float2*)&Xs[cc][t2] = xv;
            } else {
                int iy = idx - 2304;
                int cc = iy >> 5;
                int t2 = (iy & 31) * 2;
                int gy = j0 + t2;
                const float* yp = Y + (size_t)(CH * h + cc) * TT;
                float2 yv;
                if (gy + 1 < TT) yv = *(const float2*)(yp + gy);
                else { yv.x = yp[min(gy, TT - 1)]; yv.y = yp[min(gy + 1, TT - 1)]; }
                *(float2*)&Ys[cc][t2] = yv;
            }
        }
        __syncthreads();   // stage visible

#pragma unroll 4
        for (int cc = 0; cc < CH; ++cc) {
            float xv[8], yv[4];
            *(float4*)&xv[0] = *(const float4*)&Xs[cc][su * 8];
            *(float4*)&xv[4] = *(const float4*)&Xs[cc][su * 8 + 4];
            *(float4*)&yv[0] = *(const float4*)&Ys[cc][sv * 4];
#pragma unroll
            for (int a = 0; a < 8; ++a)
#pragma unroll
                for (int b = 0; b < 4; ++b)
                    s[a][b] += xv[a] * yv[b];
        }
        __syncthreads();   // reads done; stage buffer free (h=0) / dead (h=1)
    }

    // ---- S store (XOR-swizzled on 4-float granules) ----
#pragma unroll
    for (int a = 0; a < 8; ++a) {
        int row = su * 8 + a;
        int swz = ((row >> 3) & 3) << 2;
        *(float4*)&Sl[row][(sv * 4) ^ swz] = make_float4(s[a][0], s[a][1], s[a][2], s[a][3]);
    }
    __syncthreads();   // S visible

    // ---- diagonal-band dots (ascending k: bit-identical) ----
    float dot[8][4];
#pragma unroll
    for (int a = 0; a < 8; ++a)
#pragma unroll
        for (int b = 0; b < 4; ++b) dot[a][b] = 0.0f;

#pragma unroll
    for (int r = 0; r < 14; ++r) {
        int row = ri + r;          // up to 133: stray reads stay inside smem, masked
        int swz = ((row >> 3) & 3) << 2;
        float f[12];
        *(float4*)&f[0] = *(const float4*)&Sl[row][(rj)     ^ swz];
        *(float4*)&f[4] = *(const float4*)&Sl[row][(rj + 4) ^ swz];
        *(float4*)&f[8] = *(const float4*)&Sl[row][(rj + 8) ^ swz];
#pragma unroll
        for (int a = 0; a < 8; ++a) {
            const int k = r - a;
            if (k >= 0 && k < PP) {
#pragma unroll
                for (int b = 0; b < 4; ++b)
                    dot[a][b] += f[b + k];
            }
        }
    }

    // ---- epilogue: dist, column minima, optional store ----
    const int gj0 = j0 + rj;
    bool bv[4]; float syv[4];
#pragma unroll
    for (int b = 0; b < 4; ++b) {
        int lj = rj + b, gj = gj0 + b;
        bv[b] = (lj < TIJ && gj < NN);
        syv[b] = bv[b] ? sy[gj] : 0.0f;
    }
    const bool fullCols = (rj + 3 < TIJ) && (gj0 + 3 < NN);  // thread-uniform
    const bool al16 = ((gj0 & 3) == 0);                      // block-uniform (58bx mod 4 in {0,2})

    float cm[4];
#pragma unroll
    for (int b = 0; b < 4; ++b) cm[b] = __uint_as_float(0x7f800000u);

#pragma unroll
    for (int a = 0; a < 8; ++a) {
        int li = ri + a, gi = i0 + li;
        if (li >= TII || gi >= NN) continue;
        float sxi = sx[gi];
        float d4[4];
#pragma unroll
        for (int b = 0; b < 4; ++b) {
            d4[b] = (sxi + syv[b] - 2.0f * dot[a][b]) * INV_D;
            if (bv[b]) cm[b] = fminf(cm[b], d4[b]);
        }
        if (store) {
            float* drow = distbuf + (size_t)gi * TT + gj0;
            if (fullCols) {
                if (al16) {
                    *(float4*)&drow[0] = make_float4(d4[0], d4[1], d4[2], d4[3]);
                } else {   // gj0 % 4 == 2: two aligned float2
                    *(float2*)&drow[0] = make_float2(d4[0], d4[1]);
                    *(float2*)&drow[2] = make_float2(d4[2], d4[3]);
                }
            } else {
#pragma unroll
                for (int b = 0; b < 4; ++b)
                    if (bv[b]) drow[b] = d4[b];
            }
        }
    }
#pragma unroll
    for (int b = 0; b < 4; ++b)
        if (bv[b]) atomicMin(&cmin_s[rj + b], __float_as_uint(cm[b]));
    __syncthreads();   // cmin_s complete
    if (tid < TIJ) {
        int gj = j0 + tid;
        if (gj < NN) atomicMin(&colmin[gj], cmin_s[tid]);
    }
}

// ------------------------------------------------------------------
// pass2 stream: SROWS dist rows per block (validated r8). Bit-identical
// nd = d/(alpha+cm), (bits<<32)|j packing, u64-min partition-independent.
// ------------------------------------------------------------------
template<bool FULL>
__global__ __launch_bounds__(256) void pass2_stream_k(
        const float* __restrict__ distbuf, const unsigned* __restrict__ colmin,
        unsigned long long* __restrict__ packed,
        int* __restrict__ nnf, unsigned long long* __restrict__ qsum, int nrows) {
    const int i0 = blockIdx.x * SROWS;
    const float* row0 = distbuf + (size_t)i0 * TT;
    const float* cmf = (const float*)colmin;   // bit pattern of nonneg floats

    unsigned long long best[SROWS];
#pragma unroll
    for (int r = 0; r < SROWS; ++r) best[r] = ~0ULL;

    for (int jb = threadIdx.x * 8; jb < NN; jb += 2048) {
        float4 c4a = *(const float4*)(cmf + jb);
        float4 c4b = *(const float4*)(cmf + jb + 4);
        float acm[8];
#pragma unroll
        for (int e = 0; e < 8; ++e)
            acm[e] = ALPHA_C + ((e < 4) ? (&c4a.x)[e] : (&c4b.x)[e - 4]);
#pragma unroll
        for (int r = 0; r < SROWS; ++r) {
            const float* row = row0 + (size_t)r * TT;
            float4 d4a = *(const float4*)(row + jb);
            float4 d4b = *(const float4*)(row + jb + 4);
#pragma unroll
            for (int e = 0; e < 8; ++e) {
                int j = jb + e;
                if (j < NN) {
                    float d  = (e < 4) ? (&d4a.x)[e] : (&d4b.x)[e - 4];
                    float nd = d / acm[e];    // exact division — matches validated path
                    unsigned long long pk =
                        ((unsigned long long)__float_as_uint(nd) << 32) | (unsigned)j;
                    best[r] = (pk < best[r]) ? pk : best[r];
                }
            }
        }
    }
#pragma unroll
    for (int r = 0; r < SROWS; ++r)
#pragma unroll
        for (int off = 32; off > 0; off >>= 1) {
            unsigned long long o = __shfl_down(best[r], off, 64);
            best[r] = (o < best[r]) ? o : best[r];
        }
    __shared__ unsigned long long wb[4][SROWS];
    int lane = threadIdx.x & 63, wid = threadIdx.x >> 6;
    if (lane == 0) {
#pragma unroll
        for (int r = 0; r < SROWS; ++r) wb[wid][r] = best[r];
    }
    __syncthreads();
    if (threadIdx.x < SROWS) {
        int r = threadIdx.x;
        int i = i0 + r;
        if (i < nrows) {
            unsigned long long b0 = wb[0][r];
            b0 = (wb[1][r] < b0) ? wb[1][r] : b0;
            b0 = (wb[2][r] < b0) ? wb[2][r] : b0;
            b0 = (wb[3][r] < b0) ? wb[3][r] : b0;
            if (FULL) {
                int j = (int)(b0 & 0xffffffffu);
                nnf[i] = j;
                float dval = distbuf[(size_t)i * TT + j];   // bit-exact stored dist
                atomicAdd(qsum, (unsigned long long)(long long)(dval * QSCALE));
            } else {
                packed[i] = b0;
            }
        }
    }
}

// ------------------------------------------------------------------
// legacy square tile engine (hybrid fallback pass2 only) — validated,
// unchanged; produces the same dot bits as the new engine.
// ------------------------------------------------------------------
__device__ __forceinline__ void tile_dots256(const float* __restrict__ X,
                                             const float* __restrict__ Y,
                                             int i0, int j0, char* smem,
                                             float dot[8][8]) {
    float (*Xs)[SG]   = (float (*)[SG])smem;
    float (*Ys)[SG]   = (float (*)[SG])(smem + STAGE_BYTES);
    float (*Sl)[SPAD] = (float (*)[SPAD])smem;
    const int tid = threadIdx.x;

    for (int idx = tid; idx < CC * SG / 2; idx += 256) {
        int c  = idx >> 6;
        int t2 = (idx & 63) * 2;
        int gx = i0 + t2, gy = j0 + t2;
        float2 xv, yv;
        if (gx + 1 < TT) xv = *(const float2*)(X + c * TT + gx);
        else { xv.x = X[c * TT + min(gx, TT - 1)]; xv.y = X[c * TT + min(gx + 1, TT - 1)]; }
        if (gy + 1 < TT) yv = *(const float2*)(Y + c * TT + gy);
        else { yv.x = Y[c * TT + min(gy, TT - 1)]; yv.y = Y[c * TT + min(gy + 1, TT - 1)]; }
        *(float2*)&Xs[c][t2] = xv;
        *(float2*)&Ys[c][t2] = yv;
    }
    __syncthreads();

    const int su = tid >> 4, sv = tid & 15;
    float s[8][8];
#pragma unroll
    for (int a = 0; a < 8; ++a)
#pragma unroll
        for (int b = 0; b < 8; ++b) s[a][b] = 0.0f;

#pragma unroll 4
    for (int c = 0; c < CC; ++c) {
        float xv[8], yv[8];
        *(float4*)&xv[0] = *(const float4*)&Xs[c][su * 8];
        *(float4*)&xv[4] = *(const float4*)&Xs[c][su * 8 + 4];
        *(float4*)&yv[0] = *(const float4*)&Ys[c][sv * 4];
        *(float4*)&yv[4] = *(const float4*)&Ys[c][64 + sv * 4];
#pragma unroll
        for (int a = 0; a < 8; ++a)
#pragma unroll
            for (int b = 0; b < 8; ++b)
                s[a][b] += xv[a] * yv[b];
    }
    __syncthreads();

#pragma unroll
    for (int a = 0; a < 8; ++a) {
        int row = su * 8 + a;
        int swz = ((row >> 3) & 3) << 2;
        *(float4*)&Sl[row][(sv * 4) ^ swz]      = make_float4(s[a][0], s[a][1], s[a][2], s[a][3]);
        *(float4*)&Sl[row][(64 + sv * 4) ^ swz] = make_float4(s[a][4], s[a][5], s[a][6], s[a][7]);
    }
    __syncthreads();

    const int ri = (tid >> 4) * 8, rj = (tid & 15) * 8;
#pragma unroll
    for (int a = 0; a < 8; ++a)
#pragma unroll
        for (int b = 0; b < 8; ++b) dot[a][b] = 0.0f;

#pragma unroll
    for (int r = 0; r < 14; ++r) {
        int row = ri + r;
        int swz = ((row >> 3) & 3) << 2;
        float f[14];
        *(float4*)&f[0]  = *(const float4*)&Sl[row][(rj)      ^ swz];
        *(float4*)&f[4]  = *(const float4*)&Sl[row][(rj + 4)  ^ swz];
        *(float4*)&f[8]  = *(const float4*)&Sl[row][(rj + 8)  ^ swz];
        *(float2*)&f[12] = *(const float2*)&Sl[row][(rj + 12) ^ swz];
#pragma unroll
        for (int a = 0; a < 8; ++a) {
            const int k = r - a;
            if (k >= 0 && k < PP) {
#pragma unroll
                for (int b = 0; b < 8; ++b)
                    dot[a][b] += f[b + k];
            }
        }
    }
}

// ------------------------------------------------------------------
// pass2b (hybrid fallback): recompute for unstored i-tiles.
// ------------------------------------------------------------------
__global__ __launch_bounds__(256) void pass2_k(
        const float* __restrict__ X, const float* __restrict__ Y,
        const float* __restrict__ sx, const float* __restrict__ sy,
        const unsigned* __restrict__ colmin,
        unsigned long long* __restrict__ packed, int itile_ofs) {
    __shared__ __align__(16) char smem[SMEM_UNION + 1024];
    unsigned long long* pmin_s = (unsigned long long*)(smem + SMEM_UNION);

    const int i0 = (itile_ofs + blockIdx.y) * TI;
    const int j0 = blockIdx.x * TI;
    const int tid = threadIdx.x;
    if (tid < TI) pmin_s[tid] = ~0ULL;

    float dot[8][8];
    tile_dots256(X, Y, i0, j0, smem, dot);

    const int ri = (tid >> 4) * 8, rj = (tid & 15) * 8;
    const int gj0 = j0 + rj;

    bool bv[8]; float syv[8], acm[8];
#pragma unroll
    for (int b = 0; b < 8; ++b) {
        int lj = rj + b, gj = gj0 + b;
        bv[b] = (lj < TI && gj < NN);
        syv[b] = bv[b] ? sy[gj] : 0.0f;
        acm[b] = bv[b] ? (ALPHA_C + __uint_as_float(colmin[gj])) : 1.0f;
    }

#pragma unroll
    for (int a = 0; a < 8; ++a) {
        int li = ri + a, gi = i0 + li;
        if (li >= TI || gi >= NN) continue;
        float sxi = sx[gi];
        unsigned long long best = ~0ULL;
#pragma unroll
        for (int b = 0; b < 8; ++b) {
            if (bv[b]) {
                float d  = (sxi + syv[b] - 2.0f * dot[a][b]) * INV_D;
                float nd = d / acm[b];   // exact division — do NOT replace with reciprocal
                unsigned long long pk =
                    ((unsigned long long)__float_as_uint(nd) << 32) | (unsigned)(gj0 + b);
                best = (pk < best) ? pk : best;
            }
        }
        atomicMin(&pmin_s[li], best);
    }
    __syncthreads();
    if (tid < TI) {
        int gi = i0 + tid;
        if (gi < NN) atomicMin(&packed[gi], pmin_s[tid]);
    }
}

// ------------------------------------------------------------------
// finalize (hybrid path only)
// ------------------------------------------------------------------
__global__ void finalize_kernel(const float* __restrict__ X, const float* __restrict__ Y,
                                const float* __restrict__ sx, const float* __restrict__ sy,
                                const unsigned long long* __restrict__ packed,
                                int* __restrict__ nnf, unsigned long long* __restrict__ qsum) {
    int i = blockIdx.x * 256 + threadIdx.x;
    long long q = 0;
    if (i < NN) {
        int j = (int)(packed[i] & 0xffffffffu);
        nnf[i] = j;
        float dot = 0.0f;
        for (int c = 0; c < CC; ++c) {
            const float* xr = X + c * TT + i;
            const float* yr = Y + c * TT + j;
#pragma unroll
            for (int k = 0; k < PP; ++k) dot += xr[k] * yr[k];
        }
        float dval = (sx[i] + sy[j] - 2.0f * dot) * INV_D;
        q = (long long)(dval * QSCALE);
    }
    __shared__ long long red[256];
    red[threadIdx.x] = q;
    __syncthreads();
    for (int s = 128; s > 0; s >>= 1) {
        if (threadIdx.x < s) red[threadIdx.x] += red[threadIdx.x + s];
        __syncthreads();
    }
    if (threadIdx.x == 0) atomicAdd(qsum, (unsigned long long)red[0]);
}

// ------------------------------------------------------------------
// fold: gather-form overlap-add + counts + mean write
// ------------------------------------------------------------------
__global__ void fold_kernel(const float* __restrict__ Y, const int* __restrict__ nnf,
                            const unsigned long long* __restrict__ qsum,
                            float* __restrict__ out) {
    int idx = blockIdx.x * 256 + threadIdx.x;
    if (idx < CC * TT) {
        int c = idx >> 13;          // /8192
        int t = idx & (TT - 1);
        float acc = 0.0f;
        int cnt = 0;
#pragma unroll
        for (int k = 0; k < PP; ++k) {
            int i = t - k;
            if (i >= 0 && i < NN) {
                acc += Y[c * TT + nnf[i] + k];
                cnt++;
            }
        }
        out[idx] = acc / (float)cnt;
    }
    if (idx == 0) {
        double m = (double)*qsum * (1.0 / (double)QSCALE) / (double)NN;
        out[CC * TT] = (float)m;
    }
}

// ------------------------------------------------------------------
extern "C" void kernel_launch(void* const* d_in, const int* in_sizes, int n_in,
                              void* d_out, int out_size, void* d_ws, size_t ws_size,
                              hipStream_t stream) {
    const float* X = (const float*)d_in[0];
    const float* Y = (const float*)d_in[1];
    float* out = (float*)d_out;

    // ---- ws partition: dist rows at front, 192 KiB scratch at tail ----
    char* w = (char*)d_ws;
    size_t base = 0;
    if (ws_size > TAIL_BYTES) base = ((ws_size - TAIL_BYTES) / 32768) * 32768;
    unsigned long long* packed = (unsigned long long*)(w + base);            // 65536
    unsigned*           colmin = (unsigned*)(w + base + 65536);              // 32768
    float*              sx     = (float*)(w + base + 98304);                 // 32744
    float*              sy     = (float*)(w + base + 131072);                // 32744
    int*                nnf    = (int*)(w + base + 163840);                  // 32744
    unsigned long long* qsum   = (unsigned long long*)(w + base + 196600);   // 8
    float*              distbuf = (float*)w;                                 // up to base bytes

    // how many whole 122-row i-tiles of dist rows fit in [0, base)?
    const long storeRows = (long)(base / ((size_t)TT * 4));
    int storeTiles = 0;
    for (int nT = 1; nT <= NTI; ++nT) {
        long need = (long)nT * TII; if (need > NN) need = NN;
        if (need <= storeRows) storeTiles = nT; else break;
    }
    const int SR = (storeTiles * TII < NN) ? storeTiles * TII : NN;  // stored row count
    const bool full = (storeTiles >= NTI);

    prep_kernel<<<dim3((TT + 255) / 256, 2), 256, 0, stream>>>(
        X, Y, sx, sy, colmin, packed, qsum);

    pass1_k<<<NT2, 256, 0, stream>>>(X, Y, sx, sy, colmin, distbuf, storeTiles);

    if (full) {
        pass2_stream_k<true><<<(NN + SROWS - 1) / SROWS, 256, 0, stream>>>(
            distbuf, colmin, packed, nnf, qsum, NN);
    } else {
        if (SR > 0)
            pass2_stream_k<false><<<(SR + SROWS - 1) / SROWS, 256, 0, stream>>>(
                distbuf, colmin, packed, nnf, qsum, SR);
        if (storeTiles < NTI) {
            dim3 grid2(NTILE, NTILE - storeTiles);
            pass2_k<<<grid2, 256, 0, stream>>>(X, Y, sx, sy, colmin, packed, storeTiles);
        }
        finalize_kernel<<<(NN + 255) / 256, 256, 0, stream>>>(X, Y, sx, sy, packed, nnf, qsum);
    }
    fold_kernel<<<(CC * TT + 255) / 256, 256, 0, stream>>>(Y, nnf, qsum, out);
}

// Round 12
// 273.421 us; speedup vs baseline: 1.2052x; 1.2052x over previous
//
#include <hip/hip_runtime.h>
#include <stdint.h>

// Problem constants (from reference)
#define TT 8192          // time length
#define CC 72            // channels
#define PP 7             // patch size
#define NN (TT - PP + 1) // 8186 patches
#define DD (CC * PP)     // 504 patch dim

#define TI 120           // output tile (both dims) — multiple of 4 so tile
                         // origins are 16B-aligned (enables float4 staging)
#define SG 128           // staged grid = TI + 8 (>= TI+PP-1 = 126)
#define SPAD 132         // padded S row stride (floats), 16B-aligned rows
#define NTILE ((NN + TI - 1) / TI)   // 69

#define STAGE_BYTES (CC * SG * 4)            // 36864 per buffer
#define SMEM_UNION  (2 * STAGE_BYTES)        // 73728 (Xs+Ys, aliased by S)

// tail scratch block: 192 KiB total, placed at end of ws so dist can use the front
#define TAIL_BYTES 196608

#define SROWS 4          // dist rows per stream block (colmin reuse + MLP)

constexpr float INV_D = 1.0f / (float)DD;
constexpr float ALPHA_C = 0.01f;
constexpr float QSCALE = 67108864.0f;        // 2^26 fixed-point for deterministic mean

// ------------------------------------------------------------------
// prep: patch norms sx/sy; init colmin, packed, qsum. (validated)
// ------------------------------------------------------------------
__global__ void prep_kernel(const float* __restrict__ X, const float* __restrict__ Y,
                            float* __restrict__ sx, float* __restrict__ sy,
                            unsigned* __restrict__ colmin,
                            unsigned long long* __restrict__ packed,
                            unsigned long long* __restrict__ qsum) {
    int i = blockIdx.x * 256 + threadIdx.x;
    if (blockIdx.y == 0) {
        if (i == 0) *qsum = 0ULL;
        if (i < TT) { colmin[i] = 0x7f800000u; packed[i] = ~0ULL; }
        if (i < NN) {
            float ax = 0.0f;
            for (int c = 0; c < CC; ++c) {
                const float* xr = X + c * TT + i;
#pragma unroll
                for (int k = 0; k < PP; ++k) { float v = xr[k]; ax += v * v; }
            }
            sx[i] = ax;
        }
    } else {
        if (i < NN) {
            float ay = 0.0f;
            for (int c = 0; c < CC; ++c) {
                const float* yr = Y + c * TT + i;
#pragma unroll
                for (int k = 0; k < PP; ++k) { float w = yr[k]; ay += w * w; }
            }
            sy[i] = ay;
        }
    }
}

// ------------------------------------------------------------------
// tile engine, 256 threads — validated r8 core with float4 staging
// (TI=120 makes i0/j0 16B-aligned; boundary tiles take a block-uniform
// clamp path). Staged VALUES and all accumulation orders are identical
// to the validated engine -> every output bit-identical.
// 8x8 per-thread S blocking (keep: 4x8 regressed r7; reg-prefetch
// regressed r9 via VGPR 220 -> 1 block/CU; narrow-J regressed r11 via
// +34% instruction overhead).
// ------------------------------------------------------------------
__device__ __forceinline__ void tile_dots256(const float* __restrict__ X,
                                             const float* __restrict__ Y,
                                             int i0, int j0, char* smem,
                                             float dot[8][8]) {
    float (*Xs)[SG]   = (float (*)[SG])smem;
    float (*Ys)[SG]   = (float (*)[SG])(smem + STAGE_BYTES);
    float (*Sl)[SPAD] = (float (*)[SPAD])smem;   // alias over Xs/Ys
    const int tid = threadIdx.x;

    // ---- stage: 9 float4 iters per matrix; interior tiles branch-free ----
    const bool intX = (i0 + SG <= TT);   // block-uniform
    const bool intY = (j0 + SG <= TT);   // block-uniform
    if (intX) {
#pragma unroll
        for (int k = 0; k < 9; ++k) {
            int idx = tid + k * 256;
            int c  = idx >> 5;           // 32 float4 per 128-col row
            int t4 = (idx & 31) * 4;
            *(float4*)&Xs[c][t4] = *(const float4*)(X + c * TT + i0 + t4);
        }
    } else {
#pragma unroll
        for (int k = 0; k < 9; ++k) {
            int idx = tid + k * 256;
            int c  = idx >> 5;
            int t4 = (idx & 31) * 4;
            float4 xv;
#pragma unroll
            for (int e = 0; e < 4; ++e)
                (&xv.x)[e] = X[c * TT + min(i0 + t4 + e, TT - 1)];
            *(float4*)&Xs[c][t4] = xv;
        }
    }
    if (intY) {
#pragma unroll
        for (int k = 0; k < 9; ++k) {
            int idx = tid + k * 256;
            int c  = idx >> 5;
            int t4 = (idx & 31) * 4;
            *(float4*)&Ys[c][t4] = *(const float4*)(Y + c * TT + j0 + t4);
        }
    } else {
#pragma unroll
        for (int k = 0; k < 9; ++k) {
            int idx = tid + k * 256;
            int c  = idx >> 5;
            int t4 = (idx & 31) * 4;
            float4 yv;
#pragma unroll
            for (int e = 0; e < 4; ++e)
                (&yv.x)[e] = Y[c * TT + min(j0 + t4 + e, TT - 1)];
            *(float4*)&Ys[c][t4] = yv;
        }
    }
    __syncthreads();

    // ---- S compute: thread (su,sv) -> rows su*8..+7, cols {4sv..+3, 64+4sv..+3}
    const int su = tid >> 4, sv = tid & 15;
    float s[8][8];
#pragma unroll
    for (int a = 0; a < 8; ++a)
#pragma unroll
        for (int b = 0; b < 8; ++b) s[a][b] = 0.0f;

#pragma unroll 4
    for (int c = 0; c < CC; ++c) {
        float xv[8], yv[8];
        *(float4*)&xv[0] = *(const float4*)&Xs[c][su * 8];
        *(float4*)&xv[4] = *(const float4*)&Xs[c][su * 8 + 4];
        *(float4*)&yv[0] = *(const float4*)&Ys[c][sv * 4];
        *(float4*)&yv[4] = *(const float4*)&Ys[c][64 + sv * 4];
#pragma unroll
        for (int a = 0; a < 8; ++a)
#pragma unroll
            for (int b = 0; b < 8; ++b)
                s[a][b] += xv[a] * yv[b];
    }
    __syncthreads();   // stage buffers dead; safe to overwrite with S

#pragma unroll
    for (int a = 0; a < 8; ++a) {
        int row = su * 8 + a;
        int swz = ((row >> 3) & 3) << 2;
        *(float4*)&Sl[row][(sv * 4) ^ swz]      = make_float4(s[a][0], s[a][1], s[a][2], s[a][3]);
        *(float4*)&Sl[row][(64 + sv * 4) ^ swz] = make_float4(s[a][4], s[a][5], s[a][6], s[a][7]);
    }
    __syncthreads();

    // ---- diagonal-band dot accumulation (contiguous 8x8 per thread) ----
    const int ri = (tid >> 4) * 8, rj = (tid & 15) * 8;
#pragma unroll
    for (int a = 0; a < 8; ++a)
#pragma unroll
        for (int b = 0; b < 8; ++b) dot[a][b] = 0.0f;

#pragma unroll
    for (int r = 0; r < 14; ++r) {
        int row = ri + r;          // up to 133: stray reads stay inside smem, masked
        int swz = ((row >> 3) & 3) << 2;
        float f[14];
        *(float4*)&f[0]  = *(const float4*)&Sl[row][(rj)      ^ swz];
        *(float4*)&f[4]  = *(const float4*)&Sl[row][(rj + 4)  ^ swz];
        *(float4*)&f[8]  = *(const float4*)&Sl[row][(rj + 8)  ^ swz];
        *(float2*)&f[12] = *(const float2*)&Sl[row][(rj + 12) ^ swz];
#pragma unroll
        for (int a = 0; a < 8; ++a) {
            const int k = r - a;
            if (k >= 0 && k < PP) {
#pragma unroll
                for (int b = 0; b < 8; ++b)
                    dot[a][b] += f[b + k];   // ascending k: bit-identical
            }
        }
    }
}

// ------------------------------------------------------------------
// pass1 (256 threads, validated body; TI=120): column minima of dist;
// tiles with blockIdx.y < storeTiles write dist rows (bit-exact d).
// All dist stores are 16B-aligned now (gj0 = 120*bx + 8*sv).
// ------------------------------------------------------------------
__global__ __launch_bounds__(256) void pass1_k(
        const float* __restrict__ X, const float* __restrict__ Y,
        const float* __restrict__ sx, const float* __restrict__ sy,
        unsigned* __restrict__ colmin,
        float* __restrict__ distbuf, int storeTiles) {
    __shared__ __align__(16) char smem[SMEM_UNION + 1024];
    unsigned* cmin_s = (unsigned*)(smem + SMEM_UNION);
    const int tid = threadIdx.x;

    const int i0 = blockIdx.y * TI;
    const int j0 = blockIdx.x * TI;
    const bool store = ((int)blockIdx.y < storeTiles);   // block-uniform

    if (tid < 128) cmin_s[tid] = 0x7f800000u;

    float dot[8][8];
    tile_dots256(X, Y, i0, j0, smem, dot);

    const int ri = (tid >> 4) * 8, rj = (tid & 15) * 8;
    const int gj0 = j0 + rj;

    bool bv[8]; float syv[8];
#pragma unroll
    for (int b = 0; b < 8; ++b) {
        int lj = rj + b, gj = gj0 + b;
        bv[b] = (lj < TI && gj < NN);
        syv[b] = bv[b] ? sy[gj] : 0.0f;
    }
    const bool fullCols = (rj + 7 < TI) && (gj0 + 7 < NN);  // thread-uniform

    float cm[8];
#pragma unroll
    for (int b = 0; b < 8; ++b) cm[b] = __uint_as_float(0x7f800000u);

#pragma unroll
    for (int a = 0; a < 8; ++a) {
        int li = ri + a, gi = i0 + li;
        if (li >= TI || gi >= NN) continue;
        float sxi = sx[gi];
        float d8[8];
#pragma unroll
        for (int b = 0; b < 8; ++b) {
            d8[b] = (sxi + syv[b] - 2.0f * dot[a][b]) * INV_D;
            if (bv[b]) cm[b] = fminf(cm[b], d8[b]);
        }
        if (store) {
            float* drow = distbuf + (size_t)gi * TT + gj0;
            if (fullCols) {   // gj0 always 16B-aligned with TI=120
                *(float4*)&drow[0] = make_float4(d8[0], d8[1], d8[2], d8[3]);
                *(float4*)&drow[4] = make_float4(d8[4], d8[5], d8[6], d8[7]);
            } else {
#pragma unroll
                for (int b = 0; b < 8; ++b)
                    if (bv[b]) drow[b] = d8[b];
            }
        }
    }
#pragma unroll
    for (int b = 0; b < 8; ++b)
        if (bv[b]) atomicMin(&cmin_s[rj + b], __float_as_uint(cm[b]));
    __syncthreads();   // cmin_s complete
    if (tid < TI) {
        int gj = j0 + tid;
        if (gj < NN) atomicMin(&colmin[gj], cmin_s[tid]);
    }
}

// ------------------------------------------------------------------
// pass2 stream: SROWS dist rows per block (validated r8). Bit-identical
// nd = d/(alpha+cm), (bits<<32)|j packing, u64-min partition-independent.
// ------------------------------------------------------------------
template<bool FULL>
__global__ __launch_bounds__(256) void pass2_stream_k(
        const float* __restrict__ distbuf, const unsigned* __restrict__ colmin,
        unsigned long long* __restrict__ packed,
        int* __restrict__ nnf, unsigned long long* __restrict__ qsum, int nrows) {
    const int i0 = blockIdx.x * SROWS;
    const float* row0 = distbuf + (size_t)i0 * TT;
    const float* cmf = (const float*)colmin;   // bit pattern of nonneg floats

    unsigned long long best[SROWS];
#pragma unroll
    for (int r = 0; r < SROWS; ++r) best[r] = ~0ULL;

    for (int jb = threadIdx.x * 8; jb < NN; jb += 2048) {
        float4 c4a = *(const float4*)(cmf + jb);
        float4 c4b = *(const float4*)(cmf + jb + 4);
        float acm[8];
#pragma unroll
        for (int e = 0; e < 8; ++e)
            acm[e] = ALPHA_C + ((e < 4) ? (&c4a.x)[e] : (&c4b.x)[e - 4]);
#pragma unroll
        for (int r = 0; r < SROWS; ++r) {
            const float* row = row0 + (size_t)r * TT;
            float4 d4a = *(const float4*)(row + jb);
            float4 d4b = *(const float4*)(row + jb + 4);
#pragma unroll
            for (int e = 0; e < 8; ++e) {
                int j = jb + e;
                if (j < NN) {
                    float d  = (e < 4) ? (&d4a.x)[e] : (&d4b.x)[e - 4];
                    float nd = d / acm[e];    // exact division — matches validated path
                    unsigned long long pk =
                        ((unsigned long long)__float_as_uint(nd) << 32) | (unsigned)j;
                    best[r] = (pk < best[r]) ? pk : best[r];
                }
            }
        }
    }
#pragma unroll
    for (int r = 0; r < SROWS; ++r)
#pragma unroll
        for (int off = 32; off > 0; off >>= 1) {
            unsigned long long o = __shfl_down(best[r], off, 64);
            best[r] = (o < best[r]) ? o : best[r];
        }
    __shared__ unsigned long long wb[4][SROWS];
    int lane = threadIdx.x & 63, wid = threadIdx.x >> 6;
    if (lane == 0) {
#pragma unroll
        for (int r = 0; r < SROWS; ++r) wb[wid][r] = best[r];
    }
    __syncthreads();
    if (threadIdx.x < SROWS) {
        int r = threadIdx.x;
        int i = i0 + r;
        if (i < nrows) {
            unsigned long long b0 = wb[0][r];
            b0 = (wb[1][r] < b0) ? wb[1][r] : b0;
            b0 = (wb[2][r] < b0) ? wb[2][r] : b0;
            b0 = (wb[3][r] < b0) ? wb[3][r] : b0;
            if (FULL) {
                int j = (int)(b0 & 0xffffffffu);
                nnf[i] = j;
                float dval = distbuf[(size_t)i * TT + j];   // bit-exact stored dist
                atomicAdd(qsum, (unsigned long long)(long long)(dval * QSCALE));
            } else {
                packed[i] = b0;
            }
        }
    }
}

// ------------------------------------------------------------------
// pass2b (hybrid fallback): recompute for unstored i-tiles.
// ------------------------------------------------------------------
__global__ __launch_bounds__(256) void pass2_k(
        const float* __restrict__ X, const float* __restrict__ Y,
        const float* __restrict__ sx, const float* __restrict__ sy,
        const unsigned* __restrict__ colmin,
        unsigned long long* __restrict__ packed, int itile_ofs) {
    __shared__ __align__(16) char smem[SMEM_UNION + 1024];
    unsigned long long* pmin_s = (unsigned long long*)(smem + SMEM_UNION);

    const int i0 = (itile_ofs + blockIdx.y) * TI;
    const int j0 = blockIdx.x * TI;
    const int tid = threadIdx.x;
    if (tid < TI) pmin_s[tid] = ~0ULL;

    float dot[8][8];
    tile_dots256(X, Y, i0, j0, smem, dot);

    const int ri = (tid >> 4) * 8, rj = (tid & 15) * 8;
    const int gj0 = j0 + rj;

    bool bv[8]; float syv[8], acm[8];
#pragma unroll
    for (int b = 0; b < 8; ++b) {
        int lj = rj + b, gj = gj0 + b;
        bv[b] = (lj < TI && gj < NN);
        syv[b] = bv[b] ? sy[gj] : 0.0f;
        acm[b] = bv[b] ? (ALPHA_C + __uint_as_float(colmin[gj])) : 1.0f;
    }

#pragma unroll
    for (int a = 0; a < 8; ++a) {
        int li = ri + a, gi = i0 + li;
        if (li >= TI || gi >= NN) continue;
        float sxi = sx[gi];
        unsigned long long best = ~0ULL;
#pragma unroll
        for (int b = 0; b < 8; ++b) {
            if (bv[b]) {
                float d  = (sxi + syv[b] - 2.0f * dot[a][b]) * INV_D;
                float nd = d / acm[b];   // exact division — do NOT replace with reciprocal
                unsigned long long pk =
                    ((unsigned long long)__float_as_uint(nd) << 32) | (unsigned)(gj0 + b);
                best = (pk < best) ? pk : best;
            }
        }
        atomicMin(&pmin_s[li], best);
    }
    __syncthreads();
    if (tid < TI) {
        int gi = i0 + tid;
        if (gi < NN) atomicMin(&packed[gi], pmin_s[tid]);
    }
}

// ------------------------------------------------------------------
// finalize (hybrid path only)
// ------------------------------------------------------------------
__global__ void finalize_kernel(const float* __restrict__ X, const float* __restrict__ Y,
                                const float* __restrict__ sx, const float* __restrict__ sy,
                                const unsigned long long* __restrict__ packed,
                                int* __restrict__ nnf, unsigned long long* __restrict__ qsum) {
    int i = blockIdx.x * 256 + threadIdx.x;
    long long q = 0;
    if (i < NN) {
        int j = (int)(packed[i] & 0xffffffffu);
        nnf[i] = j;
        float dot = 0.0f;
        for (int c = 0; c < CC; ++c) {
            const float* xr = X + c * TT + i;
            const float* yr = Y + c * TT + j;
#pragma unroll
            for (int k = 0; k < PP; ++k) dot += xr[k] * yr[k];
        }
        float dval = (sx[i] + sy[j] - 2.0f * dot) * INV_D;
        q = (long long)(dval * QSCALE);
    }
    __shared__ long long red[256];
    red[threadIdx.x] = q;
    __syncthreads();
    for (int s = 128; s > 0; s >>= 1) {
        if (threadIdx.x < s) red[threadIdx.x] += red[threadIdx.x + s];
        __syncthreads();
    }
    if (threadIdx.x == 0) atomicAdd(qsum, (unsigned long long)red[0]);
}

// ------------------------------------------------------------------
// fold: gather-form overlap-add + counts + mean write
// ------------------------------------------------------------------
__global__ void fold_kernel(const float* __restrict__ Y, const int* __restrict__ nnf,
                            const unsigned long long* __restrict__ qsum,
                            float* __restrict__ out) {
    int idx = blockIdx.x * 256 + threadIdx.x;
    if (idx < CC * TT) {
        int c = idx >> 13;          // /8192
        int t = idx & (TT - 1);
        float acc = 0.0f;
        int cnt = 0;
#pragma unroll
        for (int k = 0; k < PP; ++k) {
            int i = t - k;
            if (i >= 0 && i < NN) {
                acc += Y[c * TT + nnf[i] + k];
                cnt++;
            }
        }
        out[idx] = acc / (float)cnt;
    }
    if (idx == 0) {
        double m = (double)*qsum * (1.0 / (double)QSCALE) / (double)NN;
        out[CC * TT] = (float)m;
    }
}

// ------------------------------------------------------------------
extern "C" void kernel_launch(void* const* d_in, const int* in_sizes, int n_in,
                              void* d_out, int out_size, void* d_ws, size_t ws_size,
                              hipStream_t stream) {
    const float* X = (const float*)d_in[0];
    const float* Y = (const float*)d_in[1];
    float* out = (float*)d_out;

    // ---- ws partition: dist rows at front, 192 KiB scratch at tail ----
    char* w = (char*)d_ws;
    size_t base = 0;
    if (ws_size > TAIL_BYTES) base = ((ws_size - TAIL_BYTES) / 32768) * 32768;
    unsigned long long* packed = (unsigned long long*)(w + base);            // 65536
    unsigned*           colmin = (unsigned*)(w + base + 65536);              // 32768
    float*              sx     = (float*)(w + base + 98304);                 // 32744
    float*              sy     = (float*)(w + base + 131072);                // 32744
    int*                nnf    = (int*)(w + base + 163840);                  // 32744
    unsigned long long* qsum   = (unsigned long long*)(w + base + 196600);   // 8
    float*              distbuf = (float*)w;                                 // up to base bytes

    // how many whole i-tiles of dist rows fit in [0, base)?
    const long storeRows = (long)(base / ((size_t)TT * 4));
    int storeTiles = 0;
    for (int nT = 1; nT <= NTILE; ++nT) {
        long need = (long)nT * TI; if (need > NN) need = NN;
        if (need <= storeRows) storeTiles = nT; else break;
    }
    const int SR = (storeTiles * TI < NN) ? storeTiles * TI : NN;  // stored row count
    const bool full = (storeTiles >= NTILE);

    prep_kernel<<<dim3((TT + 255) / 256, 2), 256, 0, stream>>>(
        X, Y, sx, sy, colmin, packed, qsum);

    dim3 grid(NTILE, NTILE);
    pass1_k<<<grid, 256, 0, stream>>>(X, Y, sx, sy, colmin, distbuf, storeTiles);

    if (full) {
        pass2_stream_k<true><<<(NN + SROWS - 1) / SROWS, 256, 0, stream>>>(
            distbuf, colmin, packed, nnf, qsum, NN);
    } else {
        if (SR > 0)
            pass2_stream_k<false><<<(SR + SROWS - 1) / SROWS, 256, 0, stream>>>(
                distbuf, colmin, packed, nnf, qsum, SR);
        if (storeTiles < NTILE) {
            dim3 grid2(NTILE, NTILE - storeTiles);
            pass2_k<<<grid2, 256, 0, stream>>>(X, Y, sx, sy, colmin, packed, storeTiles);
        }
        finalize_kernel<<<(NN + 255) / 256, 256, 0, stream>>>(X, Y, sx, sy, packed, nnf, qsum);
    }
    fold_kernel<<<(CC * TT + 255) / 256, 256, 0, stream>>>(Y, nnf, qsum, out);
}

// Round 14
// 267.873 us; speedup vs baseline: 1.2301x; 1.0207x over previous
//
#include <hip/hip_runtime.h>
#include <stdint.h>

// Problem constants (from reference)
#define TT 8192          // time length
#define CC 72            // channels
#define PP 7             // patch size
#define NN (TT - PP + 1) // 8186 patches
#define DD (CC * PP)     // 504 patch dim

#define TI 120           // output tile (both dims) — multiple of 4 so tile
                         // origins are 16B-aligned (enables float4 staging)
#define SG 128           // staged grid = TI + 8 (>= TI+PP-1 = 126)
#define SPAD 132         // padded S row stride (floats), 16B-aligned rows
#define NTILE ((NN + TI - 1) / TI)   // 69

#define STAGE_BYTES (CC * SG * 4)            // 36864 per buffer
#define SMEM_UNION  (2 * STAGE_BYTES)        // 73728 (Xs+Ys, aliased by S)

// tail scratch block: 192 KiB total, placed at end of ws so dist can use the front
#define TAIL_BYTES 196608

#define SROWS 8          // dist rows per stream block (colmin reuse + MLP)

// native clang vector type: required by __builtin_nontemporal_* (HIP float4
// is a struct and is rejected). Same 16B layout/alignment as float4.
typedef float nfloat4 __attribute__((ext_vector_type(4)));

constexpr float INV_D = 1.0f / (float)DD;
constexpr float ALPHA_C = 0.01f;
constexpr float QSCALE = 67108864.0f;        // 2^26 fixed-point for deterministic mean

// ------------------------------------------------------------------
// prep: patch norms sx/sy; init colmin, packed, qsum. (validated)
// ------------------------------------------------------------------
__global__ void prep_kernel(const float* __restrict__ X, const float* __restrict__ Y,
                            float* __restrict__ sx, float* __restrict__ sy,
                            unsigned* __restrict__ colmin,
                            unsigned long long* __restrict__ packed,
                            unsigned long long* __restrict__ qsum) {
    int i = blockIdx.x * 256 + threadIdx.x;
    if (blockIdx.y == 0) {
        if (i == 0) *qsum = 0ULL;
        if (i < TT) { colmin[i] = 0x7f800000u; packed[i] = ~0ULL; }
        if (i < NN) {
            float ax = 0.0f;
            for (int c = 0; c < CC; ++c) {
                const float* xr = X + c * TT + i;
#pragma unroll
                for (int k = 0; k < PP; ++k) { float v = xr[k]; ax += v * v; }
            }
            sx[i] = ax;
        }
    } else {
        if (i < NN) {
            float ay = 0.0f;
            for (int c = 0; c < CC; ++c) {
                const float* yr = Y + c * TT + i;
#pragma unroll
                for (int k = 0; k < PP; ++k) { float w = yr[k]; ay += w * w; }
            }
            sy[i] = ay;
        }
    }
}

// ------------------------------------------------------------------
// tile engine, 256 threads — validated r12 core (float4 staging, TI=120).
// Staged VALUES and all accumulation orders identical to the validated
// engine -> every output bit-identical. Keep 8x8 per-thread blocking
// (4x8 regressed r7; reg-prefetch regressed r9; narrow-J regressed r11).
// ------------------------------------------------------------------
__device__ __forceinline__ void tile_dots256(const float* __restrict__ X,
                                             const float* __restrict__ Y,
                                             int i0, int j0, char* smem,
                                             float dot[8][8]) {
    float (*Xs)[SG]   = (float (*)[SG])smem;
    float (*Ys)[SG]   = (float (*)[SG])(smem + STAGE_BYTES);
    float (*Sl)[SPAD] = (float (*)[SPAD])smem;   // alias over Xs/Ys
    const int tid = threadIdx.x;

    // ---- stage: 9 float4 iters per matrix; interior tiles branch-free ----
    const bool intX = (i0 + SG <= TT);   // block-uniform
    const bool intY = (j0 + SG <= TT);   // block-uniform
    if (intX) {
#pragma unroll
        for (int k = 0; k < 9; ++k) {
            int idx = tid + k * 256;
            int c  = idx >> 5;           // 32 float4 per 128-col row
            int t4 = (idx & 31) * 4;
            *(float4*)&Xs[c][t4] = *(const float4*)(X + c * TT + i0 + t4);
        }
    } else {
#pragma unroll
        for (int k = 0; k < 9; ++k) {
            int idx = tid + k * 256;
            int c  = idx >> 5;
            int t4 = (idx & 31) * 4;
            float4 xv;
#pragma unroll
            for (int e = 0; e < 4; ++e)
                (&xv.x)[e] = X[c * TT + min(i0 + t4 + e, TT - 1)];
            *(float4*)&Xs[c][t4] = xv;
        }
    }
    if (intY) {
#pragma unroll
        for (int k = 0; k < 9; ++k) {
            int idx = tid + k * 256;
            int c  = idx >> 5;
            int t4 = (idx & 31) * 4;
            *(float4*)&Ys[c][t4] = *(const float4*)(Y + c * TT + j0 + t4);
        }
    } else {
#pragma unroll
        for (int k = 0; k < 9; ++k) {
            int idx = tid + k * 256;
            int c  = idx >> 5;
            int t4 = (idx & 31) * 4;
            float4 yv;
#pragma unroll
            for (int e = 0; e < 4; ++e)
                (&yv.x)[e] = Y[c * TT + min(j0 + t4 + e, TT - 1)];
            *(float4*)&Ys[c][t4] = yv;
        }
    }
    __syncthreads();

    // ---- S compute: thread (su,sv) -> rows su*8..+7, cols {4sv..+3, 64+4sv..+3}
    const int su = tid >> 4, sv = tid & 15;
    float s[8][8];
#pragma unroll
    for (int a = 0; a < 8; ++a)
#pragma unroll
        for (int b = 0; b < 8; ++b) s[a][b] = 0.0f;

#pragma unroll 4
    for (int c = 0; c < CC; ++c) {
        float xv[8], yv[8];
        *(float4*)&xv[0] = *(const float4*)&Xs[c][su * 8];
        *(float4*)&xv[4] = *(const float4*)&Xs[c][su * 8 + 4];
        *(float4*)&yv[0] = *(const float4*)&Ys[c][sv * 4];
        *(float4*)&yv[4] = *(const float4*)&Ys[c][64 + sv * 4];
#pragma unroll
        for (int a = 0; a < 8; ++a)
#pragma unroll
            for (int b = 0; b < 8; ++b)
                s[a][b] += xv[a] * yv[b];
    }
    __syncthreads();   // stage buffers dead; safe to overwrite with S

#pragma unroll
    for (int a = 0; a < 8; ++a) {
        int row = su * 8 + a;
        int swz = ((row >> 3) & 3) << 2;
        *(float4*)&Sl[row][(sv * 4) ^ swz]      = make_float4(s[a][0], s[a][1], s[a][2], s[a][3]);
        *(float4*)&Sl[row][(64 + sv * 4) ^ swz] = make_float4(s[a][4], s[a][5], s[a][6], s[a][7]);
    }
    __syncthreads();

    // ---- diagonal-band dot accumulation (contiguous 8x8 per thread) ----
    const int ri = (tid >> 4) * 8, rj = (tid & 15) * 8;
#pragma unroll
    for (int a = 0; a < 8; ++a)
#pragma unroll
        for (int b = 0; b < 8; ++b) dot[a][b] = 0.0f;

#pragma unroll
    for (int r = 0; r < 14; ++r) {
        int row = ri + r;          // up to 133: stray reads stay inside smem, masked
        int swz = ((row >> 3) & 3) << 2;
        float f[14];
        *(float4*)&f[0]  = *(const float4*)&Sl[row][(rj)      ^ swz];
        *(float4*)&f[4]  = *(const float4*)&Sl[row][(rj + 4)  ^ swz];
        *(float4*)&f[8]  = *(const float4*)&Sl[row][(rj + 8)  ^ swz];
        *(float2*)&f[12] = *(const float2*)&Sl[row][(rj + 12) ^ swz];
#pragma unroll
        for (int a = 0; a < 8; ++a) {
            const int k = r - a;
            if (k >= 0 && k < PP) {
#pragma unroll
                for (int b = 0; b < 8; ++b)
                    dot[a][b] += f[b + k];   // ascending k: bit-identical
            }
        }
    }
}

// ------------------------------------------------------------------
// pass1 (validated r12 body): column minima of dist; tiles with
// blockIdx.y < storeTiles write dist rows (bit-exact d). Dist stores
// are NONTEMPORAL (one-shot 264 MB stream, consumed once much later —
// keep it out of L2; identical bits, pure cache hint).
// ------------------------------------------------------------------
__global__ __launch_bounds__(256) void pass1_k(
        const float* __restrict__ X, const float* __restrict__ Y,
        const float* __restrict__ sx, const float* __restrict__ sy,
        unsigned* __restrict__ colmin,
        float* __restrict__ distbuf, int storeTiles) {
    __shared__ __align__(16) char smem[SMEM_UNION + 1024];
    unsigned* cmin_s = (unsigned*)(smem + SMEM_UNION);
    const int tid = threadIdx.x;

    const int i0 = blockIdx.y * TI;
    const int j0 = blockIdx.x * TI;
    const bool store = ((int)blockIdx.y < storeTiles);   // block-uniform

    if (tid < 128) cmin_s[tid] = 0x7f800000u;

    float dot[8][8];
    tile_dots256(X, Y, i0, j0, smem, dot);

    const int ri = (tid >> 4) * 8, rj = (tid & 15) * 8;
    const int gj0 = j0 + rj;

    bool bv[8]; float syv[8];
#pragma unroll
    for (int b = 0; b < 8; ++b) {
        int lj = rj + b, gj = gj0 + b;
        bv[b] = (lj < TI && gj < NN);
        syv[b] = bv[b] ? sy[gj] : 0.0f;
    }
    const bool fullCols = (rj + 7 < TI) && (gj0 + 7 < NN);  // thread-uniform

    float cm[8];
#pragma unroll
    for (int b = 0; b < 8; ++b) cm[b] = __uint_as_float(0x7f800000u);

#pragma unroll
    for (int a = 0; a < 8; ++a) {
        int li = ri + a, gi = i0 + li;
        if (li >= TI || gi >= NN) continue;
        float sxi = sx[gi];
        float d8[8];
#pragma unroll
        for (int b = 0; b < 8; ++b) {
            d8[b] = (sxi + syv[b] - 2.0f * dot[a][b]) * INV_D;
            if (bv[b]) cm[b] = fminf(cm[b], d8[b]);
        }
        if (store) {
            float* drow = distbuf + (size_t)gi * TT + gj0;
            if (fullCols) {   // gj0 always 16B-aligned with TI=120
                nfloat4 v0 = { d8[0], d8[1], d8[2], d8[3] };
                nfloat4 v1 = { d8[4], d8[5], d8[6], d8[7] };
                __builtin_nontemporal_store(v0, (nfloat4*)&drow[0]);
                __builtin_nontemporal_store(v1, (nfloat4*)&drow[4]);
            } else {
#pragma unroll
                for (int b = 0; b < 8; ++b)
                    if (bv[b]) __builtin_nontemporal_store(d8[b], &drow[b]);
            }
        }
    }
#pragma unroll
    for (int b = 0; b < 8; ++b)
        if (bv[b]) atomicMin(&cmin_s[rj + b], __float_as_uint(cm[b]));
    __syncthreads();   // cmin_s complete
    if (tid < TI) {
        int gj = j0 + tid;
        if (gj < NN) atomicMin(&colmin[gj], cmin_s[tid]);
    }
}

// ------------------------------------------------------------------
// pass2 stream: SROWS dist rows per block (colmin loads amortized 8x,
// 18 outstanding loads/iter). Nontemporal dist reads (one-shot stream).
// Same nd = d/(alpha+cm) and (bits<<32)|j packing; u64-min is
// partition-independent -> per-row result bit-identical. Tail rows
// clamp their read pointer to nrows-1 (results discarded by the
// i<nrows write guard) so no read exceeds the NN-row allocation.
// ------------------------------------------------------------------
template<bool FULL>
__global__ __launch_bounds__(256) void pass2_stream_k(
        const float* __restrict__ distbuf, const unsigned* __restrict__ colmin,
        unsigned long long* __restrict__ packed,
        int* __restrict__ nnf, unsigned long long* __restrict__ qsum, int nrows) {
    const int i0 = blockIdx.x * SROWS;
    const float* cmf = (const float*)colmin;   // bit pattern of nonneg floats

    const float* rowp[SROWS];
#pragma unroll
    for (int r = 0; r < SROWS; ++r)
        rowp[r] = distbuf + (size_t)min(i0 + r, nrows - 1) * TT;

    unsigned long long best[SROWS];
#pragma unroll
    for (int r = 0; r < SROWS; ++r) best[r] = ~0ULL;

    for (int jb = threadIdx.x * 8; jb < NN; jb += 2048) {
        float4 c4a = *(const float4*)(cmf + jb);
        float4 c4b = *(const float4*)(cmf + jb + 4);
        float acm[8];
#pragma unroll
        for (int e = 0; e < 8; ++e)
            acm[e] = ALPHA_C + ((e < 4) ? (&c4a.x)[e] : (&c4b.x)[e - 4]);
#pragma unroll
        for (int r = 0; r < SROWS; ++r) {
            nfloat4 d4a = __builtin_nontemporal_load((const nfloat4*)(rowp[r] + jb));
            nfloat4 d4b = __builtin_nontemporal_load((const nfloat4*)(rowp[r] + jb + 4));
#pragma unroll
            for (int e = 0; e < 8; ++e) {
                int j = jb + e;
                if (j < NN) {
                    float d  = (e < 4) ? d4a[e] : d4b[e - 4];
                    float nd = d / acm[e];    // exact division — matches validated path
                    unsigned long long pk =
                        ((unsigned long long)__float_as_uint(nd) << 32) | (unsigned)j;
                    best[r] = (pk < best[r]) ? pk : best[r];
                }
            }
        }
    }
#pragma unroll
    for (int r = 0; r < SROWS; ++r)
#pragma unroll
        for (int off = 32; off > 0; off >>= 1) {
            unsigned long long o = __shfl_down(best[r], off, 64);
            best[r] = (o < best[r]) ? o : best[r];
        }
    __shared__ unsigned long long wb[4][SROWS];
    int lane = threadIdx.x & 63, wid = threadIdx.x >> 6;
    if (lane == 0) {
#pragma unroll
        for (int r = 0; r < SROWS; ++r) wb[wid][r] = best[r];
    }
    __syncthreads();
    if (threadIdx.x < SROWS) {
        int r = threadIdx.x;
        int i = i0 + r;
        if (i < nrows) {
            unsigned long long b0 = wb[0][r];
            b0 = (wb[1][r] < b0) ? wb[1][r] : b0;
            b0 = (wb[2][r] < b0) ? wb[2][r] : b0;
            b0 = (wb[3][r] < b0) ? wb[3][r] : b0;
            if (FULL) {
                int j = (int)(b0 & 0xffffffffu);
                nnf[i] = j;
                float dval = distbuf[(size_t)i * TT + j];   // bit-exact stored dist
                atomicAdd(qsum, (unsigned long long)(long long)(dval * QSCALE));
            } else {
                packed[i] = b0;
            }
        }
    }
}

// ------------------------------------------------------------------
// pass2b (hybrid fallback): recompute for unstored i-tiles.
// ------------------------------------------------------------------
__global__ __launch_bounds__(256) void pass2_k(
        const float* __restrict__ X, const float* __restrict__ Y,
        const float* __restrict__ sx, const float* __restrict__ sy,
        const unsigned* __restrict__ colmin,
        unsigned long long* __restrict__ packed, int itile_ofs) {
    __shared__ __align__(16) char smem[SMEM_UNION + 1024];
    unsigned long long* pmin_s = (unsigned long long*)(smem + SMEM_UNION);

    const int i0 = (itile_ofs + blockIdx.y) * TI;
    const int j0 = blockIdx.x * TI;
    const int tid = threadIdx.x;
    if (tid < TI) pmin_s[tid] = ~0ULL;

    float dot[8][8];
    tile_dots256(X, Y, i0, j0, smem, dot);

    const int ri = (tid >> 4) * 8, rj = (tid & 15) * 8;
    const int gj0 = j0 + rj;

    bool bv[8]; float syv[8], acm[8];
#pragma unroll
    for (int b = 0; b < 8; ++b) {
        int lj = rj + b, gj = gj0 + b;
        bv[b] = (lj < TI && gj < NN);
        syv[b] = bv[b] ? sy[gj] : 0.0f;
        acm[b] = bv[b] ? (ALPHA_C + __uint_as_float(colmin[gj])) : 1.0f;
    }

#pragma unroll
    for (int a = 0; a < 8; ++a) {
        int li = ri + a, gi = i0 + li;
        if (li >= TI || gi >= NN) continue;
        float sxi = sx[gi];
        unsigned long long best = ~0ULL;
#pragma unroll
        for (int b = 0; b < 8; ++b) {
            if (bv[b]) {
                float d  = (sxi + syv[b] - 2.0f * dot[a][b]) * INV_D;
                float nd = d / acm[b];   // exact division — do NOT replace with reciprocal
                unsigned long long pk =
                    ((unsigned long long)__float_as_uint(nd) << 32) | (unsigned)(gj0 + b);
                best = (pk < best) ? pk : best;
            }
        }
        atomicMin(&pmin_s[li], best);
    }
    __syncthreads();
    if (tid < TI) {
        int gi = i0 + tid;
        if (gi < NN) atomicMin(&packed[gi], pmin_s[tid]);
    }
}

// ------------------------------------------------------------------
// finalize (hybrid path only)
// ------------------------------------------------------------------
__global__ void finalize_kernel(const float* __restrict__ X, const float* __restrict__ Y,
                                const float* __restrict__ sx, const float* __restrict__ sy,
                                const unsigned long long* __restrict__ packed,
                                int* __restrict__ nnf, unsigned long long* __restrict__ qsum) {
    int i = blockIdx.x * 256 + threadIdx.x;
    long long q = 0;
    if (i < NN) {
        int j = (int)(packed[i] & 0xffffffffu);
        nnf[i] = j;
        float dot = 0.0f;
        for (int c = 0; c < CC; ++c) {
            const float* xr = X + c * TT + i;
            const float* yr = Y + c * TT + j;
#pragma unroll
            for (int k = 0; k < PP; ++k) dot += xr[k] * yr[k];
        }
        float dval = (sx[i] + sy[j] - 2.0f * dot) * INV_D;
        q = (long long)(dval * QSCALE);
    }
    __shared__ long long red[256];
    red[threadIdx.x] = q;
    __syncthreads();
    for (int s = 128; s > 0; s >>= 1) {
        if (threadIdx.x < s) red[threadIdx.x] += red[threadIdx.x + s];
        __syncthreads();
    }
    if (threadIdx.x == 0) atomicAdd(qsum, (unsigned long long)red[0]);
}

// ------------------------------------------------------------------
// fold: gather-form overlap-add + counts + mean write
// ------------------------------------------------------------------
__global__ void fold_kernel(const float* __restrict__ Y, const int* __restrict__ nnf,
                            const unsigned long long* __restrict__ qsum,
                            float* __restrict__ out) {
    int idx = blockIdx.x * 256 + threadIdx.x;
    if (idx < CC * TT) {
        int c = idx >> 13;          // /8192
        int t = idx & (TT - 1);
        float acc = 0.0f;
        int cnt = 0;
#pragma unroll
        for (int k = 0; k < PP; ++k) {
            int i = t - k;
            if (i >= 0 && i < NN) {
                acc += Y[c * TT + nnf[i] + k];
                cnt++;
            }
        }
        out[idx] = acc / (float)cnt;
    }
    if (idx == 0) {
        double m = (double)*qsum * (1.0 / (double)QSCALE) / (double)NN;
        out[CC * TT] = (float)m;
    }
}

// ------------------------------------------------------------------
extern "C" void kernel_launch(void* const* d_in, const int* in_sizes, int n_in,
                              void* d_out, int out_size, void* d_ws, size_t ws_size,
                              hipStream_t stream) {
    const float* X = (const float*)d_in[0];
    const float* Y = (const float*)d_in[1];
    float* out = (float*)d_out;

    // ---- ws partition: dist rows at front, 192 KiB scratch at tail ----
    char* w = (char*)d_ws;
    size_t base = 0;
    if (ws_size > TAIL_BYTES) base = ((ws_size - TAIL_BYTES) / 32768) * 32768;
    unsigned long long* packed = (unsigned long long*)(w + base);            // 65536
    unsigned*           colmin = (unsigned*)(w + base + 65536);              // 32768
    float*              sx     = (float*)(w + base + 98304);                 // 32744
    float*              sy     = (float*)(w + base + 131072);                // 32744
    int*                nnf    = (int*)(w + base + 163840);                  // 32744
    unsigned long long* qsum   = (unsigned long long*)(w + base + 196600);   // 8
    float*              distbuf = (float*)w;                                 // up to base bytes

    // how many whole i-tiles of dist rows fit in [0, base)?
    const long storeRows = (long)(base / ((size_t)TT * 4));
    int storeTiles = 0;
    for (int nT = 1; nT <= NTILE; ++nT) {
        long need = (long)nT * TI; if (need > NN) need = NN;
        if (need <= storeRows) storeTiles = nT; else break;
    }
    const int SR = (storeTiles * TI < NN) ? storeTiles * TI : NN;  // stored row count
    const bool full = (storeTiles >= NTILE);

    prep_kernel<<<dim3((TT + 255) / 256, 2), 256, 0, stream>>>(
        X, Y, sx, sy, colmin, packed, qsum);

    dim3 grid(NTILE, NTILE);
    pass1_k<<<grid, 256, 0, stream>>>(X, Y, sx, sy, colmin, distbuf, storeTiles);

    if (full) {
        pass2_stream_k<true><<<(NN + SROWS - 1) / SROWS, 256, 0, stream>>>(
            distbuf, colmin, packed, nnf, qsum, NN);
    } else {
        if (SR > 0)
            pass2_stream_k<false><<<(SR + SROWS - 1) / SROWS, 256, 0, stream>>>(
                distbuf, colmin, packed, nnf, qsum, SR);
        if (storeTiles < NTILE) {
            dim3 grid2(NTILE, NTILE - storeTiles);
            pass2_k<<<grid2, 256, 0, stream>>>(X, Y, sx, sy, colmin, packed, storeTiles);
        }
        finalize_kernel<<<(NN + 255) / 256, 256, 0, stream>>>(X, Y, sx, sy, packed, nnf, qsum);
    }
    fold_kernel<<<(CC * TT + 255) / 256, 256, 0, stream>>>(Y, nnf, qsum, out);
}